// Round 5
// baseline (3513.254 us; speedup 1.0000x reference)
//
#include <hip/hip_runtime.h>

typedef __bf16 bf16;
typedef __bf16 bf16x8 __attribute__((ext_vector_type(8)));
typedef float f32x4 __attribute__((ext_vector_type(4)));
typedef unsigned int u32x4 __attribute__((ext_vector_type(4)));

#define T_STEPS 256
#define NWG 256

__device__ __forceinline__ float fast_sigmoid(float v) {
    return __fdividef(1.0f, 1.0f + __expf(-v));
}
__device__ __forceinline__ float fast_tanh(float v) {
    v = fminf(fmaxf(v, -15.0f), 15.0f);
    float e2 = __expf(2.0f * v);
    return __fdividef(e2 - 1.0f, e2 + 1.0f);
}

__global__ void init_kernel(bf16* __restrict__ hb0, unsigned int* __restrict__ bar) {
    int gid = blockIdx.x * blockDim.x + threadIdx.x;  // 32768 threads
    #pragma unroll
    for (int i = 0; i < 4; ++i) hb0[gid + i * 32768] = (bf16)0.0f;
    if (gid == 0) { bar[0] = 0u; bar[32] = 0u; bar[64] = 0u; bar[96] = 0u; }
}

// ---------------------------------------------------------------------------
// Persistent LSTM: 256 WGs x 512 thr (1/CU). WG = (mq = batch rows [32mq,+32),
// tile = hidden cols [16t,+16) x 4 gates). Wave w owns k slice [256w,+256),
// ALL 4 gates (bfrag[4][8] = 128 VGPR persistent). Waves 0-3 (x half): stage
// own LDS window + GEMM, never touch the barrier. Waves 4-7 (h half): spin
// (wave4 polls global flag, relays via LDS sentinel), then load A-frags
// DIRECTLY from MALL (sc0 sc1 dwordx4 = exact MFMA A-layout) -> MFMA. No LDS
// round-trip for h. Reduce: 4 partial bufs (pitch 66, 2-way banks = free),
// pair-merge by x-waves, combine sums 4. One relaxed RMW per WG per step.
// ---------------------------------------------------------------------------
__global__ __launch_bounds__(512, 2) void lstm_persist(
    const float* __restrict__ x,
    const float* __restrict__ Wf, const float* __restrict__ bfp,
    const float* __restrict__ Wi, const float* __restrict__ bip,
    const float* __restrict__ Wg, const float* __restrict__ bgp,
    const float* __restrict__ Wo, const float* __restrict__ bop,
    bf16* __restrict__ hb, unsigned int* __restrict__ bar)
{
    __shared__ bf16 S[32 * 1024];       // 64 KB: x half, row pitch 128 chunks, chunk c at c^(row&7)
    __shared__ float zb[4 * 2112];      // 33 KB: partial bufs [32][66] for waves 4..7
    __shared__ unsigned int lsig;       // intra-WG relay of the global flag

    const int wg   = blockIdx.x;
    const int mq   = wg & 3;
    const int tile = wg >> 2;
    const int tid  = threadIdx.x;
    const int lane = tid & 63;
    const int w    = tid >> 6;          // wave: k slice [256w, 256w+256)
    const int l16  = lane & 15;
    const int l4   = lane >> 4;
    unsigned int* mybar = bar + mq * 32;

    // ---- persistent B fragments: gate g, ks: W[n=tile*16+l16][k=256w+ks*32+l4*8]
    const float* Wptr[4] = {Wf, Wi, Wg, Wo};
    bf16x8 bfrag[4][8];
    #pragma unroll
    for (int g = 0; g < 4; ++g) {
        const float* wrow = Wptr[g] + (size_t)(tile * 16 + l16) * 2048 + 256 * w + l4 * 8;
        #pragma unroll
        for (int ks = 0; ks < 8; ++ks) {
            float4 a = *(const float4*)(wrow + ks * 32);
            float4 b = *(const float4*)(wrow + ks * 32 + 4);
            bf16x8 f;
            f[0]=(bf16)a.x; f[1]=(bf16)a.y; f[2]=(bf16)a.z; f[3]=(bf16)a.w;
            f[4]=(bf16)b.x; f[5]=(bf16)b.y; f[6]=(bf16)b.z; f[7]=(bf16)b.w;
            bfrag[g][ks] = f;
        }
    }

    // ---- combine ownership: threads 0..255 -> (row cb, col pair 2cp)
    const int cb = tid >> 3;
    const int cp = tid & 7;
    float bias0[2], bias1[2], bias2[2], bias3[2];
    if (tid < 256) {
        #pragma unroll
        for (int j = 0; j < 2; ++j) {
            int col = tile * 16 + 2 * cp + j;
            bias0[j] = bfp[col];  // gate0 -> i_t (ref naming swap)
            bias1[j] = bip[col];  // gate1 -> f_t
            bias2[j] = bgp[col];  // gate2 -> g_t
            bias3[j] = bop[col];  // gate3 -> o_t
        }
    }
    float creg0 = 0.0f, creg1 = 0.0f;

    if (tid == 0) lsig = 0u;
    __syncthreads();

    for (int t = 0; t < T_STEPS; ++t) {
        const bf16* hcur = hb + (t & 1) * 131072;
        f32x4 acc[2][4];
        #pragma unroll
        for (int mt = 0; mt < 2; ++mt)
            #pragma unroll
            for (int g = 0; g < 4; ++g) acc[mt][g] = (f32x4){0.f, 0.f, 0.f, 0.f};

        if (w < 4) {
            // ---- x path: stage OWN window (rows 0..31, chunks [32w,+32)), no barrier
            const float* xt = x + (size_t)t * 131072 + (size_t)(mq * 32) * 1024;
            #pragma unroll
            for (int i = 0; i < 16; ++i) {
                int idx = i * 64 + lane;
                int row = idx >> 5, cs = idx & 31;
                int c   = 32 * w + cs;
                const float* g0 = xt + (size_t)row * 1024 + c * 8;
                float4 v0 = *(const float4*)(g0);
                float4 v1 = *(const float4*)(g0 + 4);
                bf16x8 f;
                f[0]=(bf16)v0.x; f[1]=(bf16)v0.y; f[2]=(bf16)v0.z; f[3]=(bf16)v0.w;
                f[4]=(bf16)v1.x; f[5]=(bf16)v1.y; f[6]=(bf16)v1.z; f[7]=(bf16)v1.w;
                *(bf16x8*)(&S[row * 1024 + (c ^ (row & 7)) * 8]) = f;
            }
            // ---- x GEMM (wave reads only its own LDS writes -> no syncthreads)
            #pragma unroll
            for (int ks = 0; ks < 8; ++ks) {
                bf16x8 af[2];
                #pragma unroll
                for (int mt = 0; mt < 2; ++mt) {
                    int row = mt * 16 + l16;
                    int c   = 32 * w + ks * 4 + l4;
                    af[mt] = *(const bf16x8*)(&S[row * 1024 + (c ^ (l16 & 7)) * 8]);
                }
                #pragma unroll
                for (int mt = 0; mt < 2; ++mt)
                    #pragma unroll
                    for (int g = 0; g < 4; ++g)
                        acc[mt][g] = __builtin_amdgcn_mfma_f32_16x16x32_bf16(
                            af[mt], bfrag[g][ks], acc[mt][g], 0, 0, 0);
            }
        } else {
            // ---- h path: wait for h(t) (t=0: zeroed by init kernel)
            if (t > 0) {
                unsigned int goal = (unsigned int)t * 64u;
                if (w == 4) {
                    while (__hip_atomic_load(mybar, __ATOMIC_RELAXED, __HIP_MEMORY_SCOPE_AGENT) < goal)
                        __builtin_amdgcn_s_sleep(1);
                    if (lane == 0)
                        __hip_atomic_store(&lsig, (unsigned int)t, __ATOMIC_RELAXED,
                                           __HIP_MEMORY_SCOPE_WORKGROUP);
                } else {
                    while (__hip_atomic_load(&lsig, __ATOMIC_RELAXED, __HIP_MEMORY_SCOPE_WORKGROUP)
                           < (unsigned int)t)
                        __builtin_amdgcn_s_sleep(1);
                }
            }
            // ---- A-frags straight from MALL: lane(l16,l4) loads exactly its fragment
            u32x4 tmp[16];
            const bf16* hrow = hcur + (size_t)(mq * 32 + l16) * 1024 + (256 * w - 1024) + l4 * 8;
            #pragma unroll
            for (int ks = 0; ks < 8; ++ks) {
                #pragma unroll
                for (int mt = 0; mt < 2; ++mt) {
                    const void* g = hrow + (size_t)mt * 16 * 1024 + ks * 32;
                    asm volatile("global_load_dwordx4 %0, %1, off sc0 sc1"
                                 : "=v"(tmp[ks * 2 + mt]) : "v"(g));
                }
            }
            asm volatile("s_waitcnt vmcnt(0)" ::: "memory");
            #pragma unroll
            for (int i = 0; i < 16; ++i) asm volatile("" : "+v"(tmp[i]));
            #pragma unroll
            for (int ks = 0; ks < 8; ++ks)
                #pragma unroll
                for (int mt = 0; mt < 2; ++mt) {
                    bf16x8 af = __builtin_bit_cast(bf16x8, tmp[ks * 2 + mt]);
                    #pragma unroll
                    for (int g = 0; g < 4; ++g)
                        acc[mt][g] = __builtin_amdgcn_mfma_f32_16x16x32_bf16(
                            af, bfrag[g][ks], acc[mt][g], 0, 0, 0);
                }
            // ---- write partial buf (pitch 66: exact 2-way banks = free)
            float* pb = zb + (w - 4) * 2112;
            #pragma unroll
            for (int mt = 0; mt < 2; ++mt)
                #pragma unroll
                for (int g = 0; g < 4; ++g)
                    #pragma unroll
                    for (int r = 0; r < 4; ++r)
                        pb[(mt * 16 + l4 * 4 + r) * 66 + g * 16 + l16] = acc[mt][g][r];
        }
        __syncthreads();  // s2: h partials visible

        if (w < 4) {  // pair-merge: x-wave p += buf of wave p+4, write back merged
            float* pb = zb + w * 2112;
            #pragma unroll
            for (int mt = 0; mt < 2; ++mt)
                #pragma unroll
                for (int g = 0; g < 4; ++g)
                    #pragma unroll
                    for (int r = 0; r < 4; ++r) {
                        int o = (mt * 16 + l4 * 4 + r) * 66 + g * 16 + l16;
                        pb[o] += acc[mt][g][r];
                    }
        }
        __syncthreads();  // s3: merged bufs visible

        // ---- combine: z = sum of 4 merged bufs + bias; c in register; packed store
        if (tid < 256) {
            float hv[2];
            #pragma unroll
            for (int j = 0; j < 2; ++j) {
                int col = 2 * cp + j;
                float zi = bias0[j], zf = bias1[j], zg = bias2[j], zo = bias3[j];
                #pragma unroll
                for (int k = 0; k < 4; ++k) {
                    const float* pb = zb + k * 2112 + cb * 66;
                    zi += pb[0  + col];
                    zf += pb[16 + col];
                    zg += pb[32 + col];
                    zo += pb[48 + col];
                }
                float ig = fast_sigmoid(zi), fg = fast_sigmoid(zf);
                float gg = fast_tanh(zg),    og = fast_sigmoid(zo);
                float& cr = j ? creg1 : creg0;
                cr = fg * cr + ig * gg;
                hv[j] = og * fast_tanh(cr);
            }
            unsigned short u0 = __builtin_bit_cast(unsigned short, (bf16)hv[0]);
            unsigned short u1 = __builtin_bit_cast(unsigned short, (bf16)hv[1]);
            unsigned int packed = ((unsigned int)u1 << 16) | u0;
            unsigned int* dst = (unsigned int*)(hb + ((t + 1) & 1) * 131072
                                + (size_t)(mq * 32 + cb) * 1024 + tile * 16 + 2 * cp);
            __hip_atomic_store(dst, packed, __ATOMIC_RELAXED, __HIP_MEMORY_SCOPE_SYSTEM);
            asm volatile("s_waitcnt vmcnt(0)" ::: "memory");  // store acked at MALL
        }
        __syncthreads();  // s4: all combine stores acked
        if (tid == 0)
            __hip_atomic_fetch_add(mybar, 1u, __ATOMIC_RELAXED, __HIP_MEMORY_SCOPE_AGENT);
    }
}

// ---------------------------------------------------------------------------
// logits = h_T @ Wout^T + bout (Wout converted inline from f32).
// ---------------------------------------------------------------------------
__global__ __launch_bounds__(512) void final_gemm_kernel(
    const bf16* __restrict__ hfin, const float* __restrict__ Wout,
    const float* __restrict__ bout, float* __restrict__ logits) {
    __shared__ alignas(16) bf16 Slds[128 * 72];
    const int tid  = threadIdx.x;
    const int lane = tid & 63;
    const int wave = tid >> 6;
    const int l16  = lane & 15;
    const int l4   = lane >> 4;
    const int n0   = blockIdx.x * 16;
    f32x4 acc = (f32x4){0.f, 0.f, 0.f, 0.f};
    for (int k0 = 0; k0 < 1024; k0 += 64) {
        #pragma unroll
        for (int i = 0; i < 2; ++i) {
            int cidx = tid + i * 512;
            int row = cidx >> 3, c8 = cidx & 7;
            *(uint4*)(&Slds[row * 72 + c8 * 8]) =
                *(const uint4*)(hfin + row * 1024 + k0 + c8 * 8);
        }
        __syncthreads();
        #pragma unroll
        for (int kk = 0; kk < 64; kk += 32) {
            const float* wrow = Wout + (size_t)(n0 + l16) * 1024 + k0 + kk + l4 * 8;
            float4 w0 = *(const float4*)(wrow);
            float4 w1 = *(const float4*)(wrow + 4);
            bf16x8 bfrag;
            bfrag[0]=(bf16)w0.x; bfrag[1]=(bf16)w0.y; bfrag[2]=(bf16)w0.z; bfrag[3]=(bf16)w0.w;
            bfrag[4]=(bf16)w1.x; bfrag[5]=(bf16)w1.y; bfrag[6]=(bf16)w1.z; bfrag[7]=(bf16)w1.w;
            bf16x8 afrag = *(const bf16x8*)(&Slds[(wave * 16 + l16) * 72 + kk + l4 * 8]);
            acc = __builtin_amdgcn_mfma_f32_16x16x32_bf16(afrag, bfrag, acc, 0, 0, 0);
        }
        __syncthreads();
    }
    float bv = bout[n0 + l16];
    #pragma unroll
    for (int r = 0; r < 4; ++r) {
        int m = wave * 16 + l4 * 4 + r;
        logits[m * 1024 + n0 + l16] = acc[r] + bv;
    }
}

// ---------------------------------------------------------------------------
// Row-wise log_softmax over 1024 logits. Grid 128 (one WG per batch row).
// ---------------------------------------------------------------------------
__global__ __launch_bounds__(256) void logsoftmax_kernel(
    const float* __restrict__ logits, float* __restrict__ out) {
    int b = blockIdx.x, tid = threadIdx.x;
    int lane = tid & 63, wv = tid >> 6;
    __shared__ float red[4];
    float v[4];
    float mx = -1e30f;
    #pragma unroll
    for (int i = 0; i < 4; ++i) {
        v[i] = logits[b * 1024 + i * 256 + tid];
        mx = fmaxf(mx, v[i]);
    }
    #pragma unroll
    for (int off = 1; off < 64; off <<= 1) mx = fmaxf(mx, __shfl_xor(mx, off));
    if (lane == 0) red[wv] = mx;
    __syncthreads();
    mx = fmaxf(fmaxf(red[0], red[1]), fmaxf(red[2], red[3]));
    float s = 0.f;
    #pragma unroll
    for (int i = 0; i < 4; ++i) s += __expf(v[i] - mx);
    #pragma unroll
    for (int off = 1; off < 64; off <<= 1) s += __shfl_xor(s, off);
    __syncthreads();
    if (lane == 0) red[wv] = s;
    __syncthreads();
    s = red[0] + red[1] + red[2] + red[3];
    float lse = mx + __logf(s);
    #pragma unroll
    for (int i = 0; i < 4; ++i) out[b * 1024 + i * 256 + tid] = v[i] - lse;
}

extern "C" void kernel_launch(void* const* d_in, const int* in_sizes, int n_in,
                              void* d_out, int out_size, void* d_ws, size_t ws_size,
                              hipStream_t stream) {
    const float* x    = (const float*)d_in[0];
    const float* Wf   = (const float*)d_in[1];
    const float* bfv  = (const float*)d_in[2];
    const float* Wi   = (const float*)d_in[3];
    const float* biv  = (const float*)d_in[4];
    const float* Wg   = (const float*)d_in[5];
    const float* bgv  = (const float*)d_in[6];
    const float* Wo   = (const float*)d_in[7];
    const float* bov  = (const float*)d_in[8];
    const float* Wout = (const float*)d_in[9];
    const float* bout = (const float*)d_in[10];
    float* out = (float*)d_out;

    // ws layout (~1.1 MB)
    char* p = (char*)d_ws;
    bf16* hbuf    = (bf16*)p;  p += (size_t)2 * 131072 * 2;   // h double-buffer
    float* logits = (float*)p; p += (size_t)131072 * 4;
    unsigned int* bar = (unsigned int*)p; p += 512;           // 4 counters, 128B apart
    if (ws_size < (size_t)(p - (char*)d_ws)) return;

    init_kernel<<<128, 256, 0, stream>>>(hbuf, bar);
    lstm_persist<<<NWG, 512, 0, stream>>>(x, Wf, bfv, Wi, biv, Wg, bgv, Wo, bov,
                                          hbuf, bar);
    // t=255 writes hbuf buffer 0
    final_gemm_kernel<<<64, 512, 0, stream>>>(hbuf, Wout, bout, logits);
    logsoftmax_kernel<<<128, 256, 0, stream>>>(logits, out);
}

// Round 6
// 1524.792 us; speedup vs baseline: 2.3041x; 2.3041x over previous
//
#include <hip/hip_runtime.h>

typedef __bf16 bf16;
typedef __bf16 bf16x8 __attribute__((ext_vector_type(8)));
typedef float f32x4 __attribute__((ext_vector_type(4)));
typedef unsigned int u32x4 __attribute__((ext_vector_type(4)));

#define T_STEPS 256
#define NWG 256

__device__ __forceinline__ float fast_sigmoid(float v) {
    return __fdividef(1.0f, 1.0f + __expf(-v));
}
__device__ __forceinline__ float fast_tanh(float v) {
    v = fminf(fmaxf(v, -15.0f), 15.0f);
    float e2 = __expf(2.0f * v);
    return __fdividef(e2 - 1.0f, e2 + 1.0f);
}

// ---------------------------------------------------------------------------
// Init: convert whole x tensor to bf16 (one-time, off the recurrence chain),
// zero h buffer 0, zero flags.
// ---------------------------------------------------------------------------
__global__ void init_kernel(const float* __restrict__ x, bf16* __restrict__ xb,
                            bf16* __restrict__ hb0, unsigned int* __restrict__ flags) {
    int gid = blockIdx.x * blockDim.x + threadIdx.x;   // 4,194,304 threads
    {   // one 8-element chunk per thread: 33,554,432 els total
        const float* src = x + (size_t)gid * 8;
        float4 v0 = *(const float4*)(src);
        float4 v1 = *(const float4*)(src + 4);
        bf16x8 f;
        f[0]=(bf16)v0.x; f[1]=(bf16)v0.y; f[2]=(bf16)v0.z; f[3]=(bf16)v0.w;
        f[4]=(bf16)v1.x; f[5]=(bf16)v1.y; f[6]=(bf16)v1.z; f[7]=(bf16)v1.w;
        *(bf16x8*)(xb + (size_t)gid * 8) = f;
    }
    if (gid < 16384) *(u32x4*)(hb0 + gid * 8) = (u32x4){0u, 0u, 0u, 0u};
    if (gid < 4096)  flags[gid] = 0u;
}

// ---------------------------------------------------------------------------
// Persistent LSTM: 256 WGs x 512 thr (1/CU). WG = (mq = batch rows [32mq,+32),
// tile = hidden cols [16t,+16) x 4 gates). Wave w owns k slice [256w,+256),
// all 4 gates: bfrag[4][8] = 128 VGPR persistent.
//   Waves 0-3 (x): A-frags directly from precomputed xb (cached loads), GEMM.
//     Never touch the global sync.
//   Waves 4-7 (h): poll 64 per-producer flags (64 lanes -> 64 distinct lines,
//     plain loads, no RMW contention), stage own 256-k h window via coalesced
//     sc0sc1 dwordx4 -> LDS, ds_read A-frags, GEMM.
//   All 8 waves write partial bufs; ONE sync; combine threads sum 8 bufs,
//   gate math, packed system-scope h store; sync; tid0 stores flag = t+1
//   (plain system store -- no atomic RMW anywhere in the loop).
// ---------------------------------------------------------------------------
__global__ __launch_bounds__(512, 2) void lstm_persist(
    const bf16* __restrict__ xb,
    const float* __restrict__ Wf, const float* __restrict__ bfp,
    const float* __restrict__ Wi, const float* __restrict__ bip,
    const float* __restrict__ Wg, const float* __restrict__ bgp,
    const float* __restrict__ Wo, const float* __restrict__ bop,
    bf16* __restrict__ hb, unsigned int* __restrict__ flags)
{
    __shared__ bf16 S[4 * 32 * 264];   // 66 KB: h staging, wave-private [32][264]
    __shared__ float zb[8 * 2112];     // 66 KB: 8 partial bufs [32][66]

    const int wg   = blockIdx.x;
    const int mq   = wg & 3;
    const int tile = wg >> 2;
    const int tid  = threadIdx.x;
    const int lane = tid & 63;
    const int w    = tid >> 6;         // wave: k slice [256w, 256w+256)
    const int l16  = lane & 15;
    const int l4   = lane >> 4;

    // ---- persistent B fragments: gate g, ks: W[n=tile*16+l16][k=256w+ks*32+l4*8]
    const float* Wptr[4] = {Wf, Wi, Wg, Wo};
    bf16x8 bfrag[4][8];
    #pragma unroll
    for (int g = 0; g < 4; ++g) {
        const float* wrow = Wptr[g] + (size_t)(tile * 16 + l16) * 2048 + 256 * w + l4 * 8;
        #pragma unroll
        for (int ks = 0; ks < 8; ++ks) {
            float4 a = *(const float4*)(wrow + ks * 32);
            float4 b = *(const float4*)(wrow + ks * 32 + 4);
            bf16x8 f;
            f[0]=(bf16)a.x; f[1]=(bf16)a.y; f[2]=(bf16)a.z; f[3]=(bf16)a.w;
            f[4]=(bf16)b.x; f[5]=(bf16)b.y; f[6]=(bf16)b.z; f[7]=(bf16)b.w;
            bfrag[g][ks] = f;
        }
    }

    // ---- combine ownership: threads 0..255 -> (row cb, cols 2cp, 2cp+1)
    const int cb = tid >> 3;
    const int cp = tid & 7;
    float bias0[2], bias1[2], bias2[2], bias3[2];
    if (tid < 256) {
        #pragma unroll
        for (int j = 0; j < 2; ++j) {
            int col = tile * 16 + 2 * cp + j;
            bias0[j] = bfp[col];  // gate0 -> i_t (ref naming swap)
            bias1[j] = bip[col];  // gate1 -> f_t
            bias2[j] = bgp[col];  // gate2 -> g_t
            bias3[j] = bop[col];  // gate3 -> o_t
        }
    }
    float creg0 = 0.0f, creg1 = 0.0f;

    for (int t = 0; t < T_STEPS; ++t) {
        f32x4 acc[2][4];
        #pragma unroll
        for (int mt = 0; mt < 2; ++mt)
            #pragma unroll
            for (int g = 0; g < 4; ++g) acc[mt][g] = (f32x4){0.f, 0.f, 0.f, 0.f};

        if (w < 4) {
            // ---- x path: A-frags straight from cached xb; two halves cap regs
            const bf16* xrow = xb + (size_t)t * 131072 + (size_t)(mq * 32 + l16) * 1024
                               + 256 * w + l4 * 8;
            #pragma unroll
            for (int half = 0; half < 2; ++half) {
                bf16x8 af[4][2];
                #pragma unroll
                for (int ks = 0; ks < 4; ++ks)
                    #pragma unroll
                    for (int mt = 0; mt < 2; ++mt)
                        af[ks][mt] = *(const bf16x8*)(xrow + (half * 4 + ks) * 32
                                                      + (size_t)mt * 16 * 1024);
                #pragma unroll
                for (int ks = 0; ks < 4; ++ks)
                    #pragma unroll
                    for (int mt = 0; mt < 2; ++mt)
                        #pragma unroll
                        for (int g = 0; g < 4; ++g)
                            acc[mt][g] = __builtin_amdgcn_mfma_f32_16x16x32_bf16(
                                af[ks][mt], bfrag[g][half * 4 + ks], acc[mt][g], 0, 0, 0);
            }
        } else {
            const int hw = w - 4;
            bf16* Sw = S + hw * 32 * 264;
            // ---- poll per-producer flags: 64 lanes -> 64 distinct 64B lines
            if (t > 0) {
                const unsigned int* fl = flags + (mq * 64 + lane) * 16;
                unsigned int fv;
                do {
                    fv = __hip_atomic_load(fl, __ATOMIC_RELAXED, __HIP_MEMORY_SCOPE_SYSTEM);
                } while (__any((int)(fv < (unsigned int)t)));
            }
            // ---- stage own h window (coalesced sc0sc1 dwordx4, 2 halves)
            const bf16* hcur = hb + (t & 1) * 131072;
            #pragma unroll
            for (int half = 0; half < 2; ++half) {
                u32x4 tmp[8];
                #pragma unroll
                for (int i = 0; i < 8; ++i) {
                    int linear = half * 512 + i * 64 + lane;
                    int row = linear >> 5, chunk = linear & 31;
                    const void* g = hcur + (size_t)(mq * 32 + row) * 1024 + hw * 256 + chunk * 8;
                    asm volatile("global_load_dwordx4 %0, %1, off sc0 sc1"
                                 : "=v"(tmp[i]) : "v"(g));
                }
                asm volatile("s_waitcnt vmcnt(0)" ::: "memory");
                #pragma unroll
                for (int i = 0; i < 8; ++i) {
                    int linear = half * 512 + i * 64 + lane;
                    int row = linear >> 5, chunk = linear & 31;
                    *(u32x4*)(&Sw[row * 264 + chunk * 8]) = tmp[i];
                }
            }
            // ---- A-frags from own LDS region (wave-private -> no syncthreads)
            #pragma unroll
            for (int ks = 0; ks < 8; ++ks) {
                bf16x8 af[2];
                #pragma unroll
                for (int mt = 0; mt < 2; ++mt)
                    af[mt] = *(const bf16x8*)(&Sw[(mt * 16 + l16) * 264 + (ks * 4 + l4) * 8]);
                #pragma unroll
                for (int mt = 0; mt < 2; ++mt)
                    #pragma unroll
                    for (int g = 0; g < 4; ++g)
                        acc[mt][g] = __builtin_amdgcn_mfma_f32_16x16x32_bf16(
                            af[mt], bfrag[g][ks], acc[mt][g], 0, 0, 0);
            }
        }

        // ---- write partial buf w (pitch 66: 2-way banks = free)
        {
            float* pb = zb + w * 2112;
            #pragma unroll
            for (int mt = 0; mt < 2; ++mt)
                #pragma unroll
                for (int g = 0; g < 4; ++g)
                    #pragma unroll
                    for (int r = 0; r < 4; ++r)
                        pb[(mt * 16 + l4 * 4 + r) * 66 + g * 16 + l16] = acc[mt][g][r];
        }
        __syncthreads();  // s2: all partials visible

        // ---- combine: sum 8 bufs + bias, gates, c-reg, packed system store
        if (tid < 256) {
            float z[4][2];
            #pragma unroll
            for (int g = 0; g < 4; ++g) {
                z[g][0] = 0.f; z[g][1] = 0.f;
            }
            #pragma unroll
            for (int k = 0; k < 8; ++k) {
                const float* pb = zb + k * 2112 + cb * 66;
                #pragma unroll
                for (int g = 0; g < 4; ++g) {
                    float2 v = *(const float2*)(pb + g * 16 + 2 * cp);
                    z[g][0] += v.x; z[g][1] += v.y;
                }
            }
            float hv[2];
            #pragma unroll
            for (int j = 0; j < 2; ++j) {
                float ig = fast_sigmoid(z[0][j] + bias0[j]);
                float fg = fast_sigmoid(z[1][j] + bias1[j]);
                float gg = fast_tanh   (z[2][j] + bias2[j]);
                float og = fast_sigmoid(z[3][j] + bias3[j]);
                float& cr = j ? creg1 : creg0;
                cr = fg * cr + ig * gg;
                hv[j] = og * fast_tanh(cr);
            }
            unsigned short u0 = __builtin_bit_cast(unsigned short, (bf16)hv[0]);
            unsigned short u1 = __builtin_bit_cast(unsigned short, (bf16)hv[1]);
            unsigned int packed = ((unsigned int)u1 << 16) | u0;
            unsigned int* dst = (unsigned int*)(hb + ((t + 1) & 1) * 131072
                                + (size_t)(mq * 32 + cb) * 1024 + tile * 16 + 2 * cp);
            __hip_atomic_store(dst, packed, __ATOMIC_RELAXED, __HIP_MEMORY_SCOPE_SYSTEM);
            asm volatile("s_waitcnt vmcnt(0)" ::: "memory");  // acked at MALL
        }
        __syncthreads();  // s3: all 256 combine stores acked
        if (tid == 0)     // plain system store -- no RMW, no shared-line contention
            __hip_atomic_store(flags + (mq * 64 + tile) * 16, (unsigned int)(t + 1),
                               __ATOMIC_RELAXED, __HIP_MEMORY_SCOPE_SYSTEM);
    }
}

// ---------------------------------------------------------------------------
// logits = h_T @ Wout^T + bout (Wout converted inline from f32).
// ---------------------------------------------------------------------------
__global__ __launch_bounds__(512) void final_gemm_kernel(
    const bf16* __restrict__ hfin, const float* __restrict__ Wout,
    const float* __restrict__ bout, float* __restrict__ logits) {
    __shared__ alignas(16) bf16 Slds[128 * 72];
    const int tid  = threadIdx.x;
    const int lane = tid & 63;
    const int wave = tid >> 6;
    const int l16  = lane & 15;
    const int l4   = lane >> 4;
    const int n0   = blockIdx.x * 16;
    f32x4 acc = (f32x4){0.f, 0.f, 0.f, 0.f};
    for (int k0 = 0; k0 < 1024; k0 += 64) {
        #pragma unroll
        for (int i = 0; i < 2; ++i) {
            int cidx = tid + i * 512;
            int row = cidx >> 3, c8 = cidx & 7;
            *(uint4*)(&Slds[row * 72 + c8 * 8]) =
                *(const uint4*)(hfin + row * 1024 + k0 + c8 * 8);
        }
        __syncthreads();
        #pragma unroll
        for (int kk = 0; kk < 64; kk += 32) {
            const float* wrow = Wout + (size_t)(n0 + l16) * 1024 + k0 + kk + l4 * 8;
            float4 w0 = *(const float4*)(wrow);
            float4 w1 = *(const float4*)(wrow + 4);
            bf16x8 bfrag;
            bfrag[0]=(bf16)w0.x; bfrag[1]=(bf16)w0.y; bfrag[2]=(bf16)w0.z; bfrag[3]=(bf16)w0.w;
            bfrag[4]=(bf16)w1.x; bfrag[5]=(bf16)w1.y; bfrag[6]=(bf16)w1.z; bfrag[7]=(bf16)w1.w;
            bf16x8 afrag = *(const bf16x8*)(&Slds[(wave * 16 + l16) * 72 + kk + l4 * 8]);
            acc = __builtin_amdgcn_mfma_f32_16x16x32_bf16(afrag, bfrag, acc, 0, 0, 0);
        }
        __syncthreads();
    }
    float bv = bout[n0 + l16];
    #pragma unroll
    for (int r = 0; r < 4; ++r) {
        int m = wave * 16 + l4 * 4 + r;
        logits[m * 1024 + n0 + l16] = acc[r] + bv;
    }
}

// ---------------------------------------------------------------------------
// Row-wise log_softmax over 1024 logits. Grid 128 (one WG per batch row).
// ---------------------------------------------------------------------------
__global__ __launch_bounds__(256) void logsoftmax_kernel(
    const float* __restrict__ logits, float* __restrict__ out) {
    int b = blockIdx.x, tid = threadIdx.x;
    int lane = tid & 63, wv = tid >> 6;
    __shared__ float red[4];
    float v[4];
    float mx = -1e30f;
    #pragma unroll
    for (int i = 0; i < 4; ++i) {
        v[i] = logits[b * 1024 + i * 256 + tid];
        mx = fmaxf(mx, v[i]);
    }
    #pragma unroll
    for (int off = 1; off < 64; off <<= 1) mx = fmaxf(mx, __shfl_xor(mx, off));
    if (lane == 0) red[wv] = mx;
    __syncthreads();
    mx = fmaxf(fmaxf(red[0], red[1]), fmaxf(red[2], red[3]));
    float s = 0.f;
    #pragma unroll
    for (int i = 0; i < 4; ++i) s += __expf(v[i] - mx);
    #pragma unroll
    for (int off = 1; off < 64; off <<= 1) s += __shfl_xor(s, off);
    __syncthreads();
    if (lane == 0) red[wv] = s;
    __syncthreads();
    s = red[0] + red[1] + red[2] + red[3];
    float lse = mx + __logf(s);
    #pragma unroll
    for (int i = 0; i < 4; ++i) out[b * 1024 + i * 256 + tid] = v[i] - lse;
}

extern "C" void kernel_launch(void* const* d_in, const int* in_sizes, int n_in,
                              void* d_out, int out_size, void* d_ws, size_t ws_size,
                              hipStream_t stream) {
    const float* x    = (const float*)d_in[0];
    const float* Wf   = (const float*)d_in[1];
    const float* bfv  = (const float*)d_in[2];
    const float* Wi   = (const float*)d_in[3];
    const float* biv  = (const float*)d_in[4];
    const float* Wg   = (const float*)d_in[5];
    const float* bgv  = (const float*)d_in[6];
    const float* Wo   = (const float*)d_in[7];
    const float* bov  = (const float*)d_in[8];
    const float* Wout = (const float*)d_in[9];
    const float* bout = (const float*)d_in[10];
    float* out = (float*)d_out;

    // ws layout (~68 MB)
    char* p = (char*)d_ws;
    bf16* xb      = (bf16*)p;  p += (size_t)T_STEPS * 131072 * 2;   // 67 MB bf16 x
    bf16* hbuf    = (bf16*)p;  p += (size_t)2 * 131072 * 2;         // h double-buffer
    float* logits = (float*)p; p += (size_t)131072 * 4;
    unsigned int* flags = (unsigned int*)p; p += 4096 * 4;          // 4 groups x 64 tiles, 64B apart
    if (ws_size < (size_t)(p - (char*)d_ws)) return;

    init_kernel<<<16384, 256, 0, stream>>>(x, xb, hbuf, flags);
    lstm_persist<<<NWG, 512, 0, stream>>>(xb, Wf, bfv, Wi, biv, Wg, bgv, Wo, bov,
                                          hbuf, flags);
    // t=255 writes hbuf buffer 0
    final_gemm_kernel<<<64, 512, 0, stream>>>(hbuf, Wout, bout, logits);
    logsoftmax_kernel<<<128, 256, 0, stream>>>(logits, out);
}